// Round 5
// baseline (5247.441 us; speedup 1.0000x reference)
//
#include <hip/hip_runtime.h>
#include <cstdint>

#define N_PTS 100000
#define N_EDGE 800000
#define IMG_W 1216
#define IMG_H 240
#define OW 304
#define OH 60
#define CHUNK 32
#define BIN_BLOCKS 391   // ceil(N_PTS/256)

typedef _Float16 f16;
typedef _Float16 f16x8 __attribute__((ext_vector_type(8)));
typedef float f32x4 __attribute__((ext_vector_type(4)));

__device__ __forceinline__ void atomicMaxF(float* addr, float v) {
    // float max via int max (v>=0) / uint min (v<0); exact, order-independent
    if (v >= 0.0f) atomicMax((int*)addr, __float_as_int(v));
    else atomicMin((unsigned int*)addr, __float_as_uint(v));
}

// ---------------- per-node kernel: A[n] = X[n]@w1_x + pos[n]@w1_p + b1 (f16) ----------------
template<int DIN_X, int DOUT>
__global__ __launch_bounds__(256)
void node_kernel(const float* __restrict__ X, const float* __restrict__ pos,
                 const float* __restrict__ w1, const float* __restrict__ b1,
                 f16* __restrict__ A)
{
    constexpr int M = 8;
    constexpr int R = 256 / DOUT;
    constexpr int RR = (R < 1) ? 1 : R;
    constexpr int MN = M / RR;
    const int tid = threadIdx.x;
    const int c = tid % DOUT;
    const int r = tid / DOUT;
    const long n0 = (long)blockIdx.x * M;

    __shared__ float xs[M][DIN_X];
    __shared__ float ps[M][4];

    for (int idx = tid; idx < M * DIN_X; idx += 256) {
        int m = idx / DIN_X, k = idx % DIN_X;
        long n = n0 + m;
        xs[m][k] = (n < N_PTS) ? X[n * DIN_X + k] : 0.0f;
    }
    for (int idx = tid; idx < M * 3; idx += 256) {
        int m = idx / 3, k = idx % 3;
        long n = n0 + m;
        ps[m][k] = (n < N_PTS) ? pos[n * 3 + k] : 0.0f;
    }
    __syncthreads();

    float acc[MN];
#pragma unroll
    for (int mi = 0; mi < MN; ++mi) acc[mi] = b1[c];

    for (int k = 0; k < DIN_X; ++k) {
        float wv = w1[k * DOUT + c];
#pragma unroll
        for (int mi = 0; mi < MN; ++mi)
            acc[mi] += xs[r * MN + mi][k] * wv;
    }
#pragma unroll
    for (int k = 0; k < 3; ++k) {
        float wv = w1[(DIN_X + k) * DOUT + c];
#pragma unroll
        for (int mi = 0; mi < MN; ++mi)
            acc[mi] += ps[r * MN + mi][k] * wv;
    }
#pragma unroll
    for (int mi = 0; mi < MN; ++mi) {
        long n = n0 + r * MN + mi;
        if (n < N_PTS) A[n * DOUT + c] = (f16)acc[mi];
    }
}

// ---------------- w2 -> f16 transpose: w2t[n*D+k] = (f16)w2[k*D+n] ----------------
__global__ void cvt_w2(const float* __restrict__ w2, f16* __restrict__ w2t, int D)
{
    int i = blockIdx.x * 256 + threadIdx.x;
    if (i >= D * D) return;
    int n = i / D, k = i % D;
    w2t[i] = (f16)w2[k * D + n];
}

// ---------------- counting sort of edges by dst ----------------
__global__ void hist_kernel(const int* __restrict__ ei, int* __restrict__ hist)
{
    int e = blockIdx.x * 256 + threadIdx.x;
    if (e < N_EDGE) atomicAdd(&hist[ei[N_EDGE + e]], 1);
}

__global__ void bsum_kernel(const int* __restrict__ hist, int* __restrict__ bsum)
{
    __shared__ int s[256];
    int i = blockIdx.x * 256 + threadIdx.x;
    s[threadIdx.x] = (i < N_PTS) ? hist[i] : 0;
    __syncthreads();
    for (int off = 128; off > 0; off >>= 1) {
        if (threadIdx.x < off) s[threadIdx.x] += s[threadIdx.x + off];
        __syncthreads();
    }
    if (threadIdx.x == 0) bsum[blockIdx.x] = s[0];
}

__global__ void scan_bsum_kernel(int* __restrict__ bsum)
{
    __shared__ int s[512];
    int t = threadIdx.x;
    int v = (t < BIN_BLOCKS) ? bsum[t] : 0;
    s[t] = v;
    __syncthreads();
    for (int off = 1; off < 512; off <<= 1) {
        int u = (t >= off) ? s[t - off] : 0;
        __syncthreads();
        s[t] += u;
        __syncthreads();
    }
    if (t < BIN_BLOCKS) bsum[t] = s[t] - v;   // exclusive
}

__global__ void rowptr_kernel(const int* __restrict__ hist, const int* __restrict__ bsum,
                              int* __restrict__ woff)
{
    __shared__ int s[256];
    int i = blockIdx.x * 256 + threadIdx.x;
    int v = (i < N_PTS) ? hist[i] : 0;
    s[threadIdx.x] = v;
    __syncthreads();
    for (int off = 1; off < 256; off <<= 1) {
        int u = (threadIdx.x >= off) ? s[threadIdx.x - off] : 0;
        __syncthreads();
        s[threadIdx.x] += u;
        __syncthreads();
    }
    if (i < N_PTS) woff[i] = bsum[blockIdx.x] + s[threadIdx.x] - v;  // exclusive
}

__global__ void scatter_edges_kernel(const int* __restrict__ ei, int* __restrict__ woff,
                                     int* __restrict__ srcS, int* __restrict__ dstS)
{
    int e = blockIdx.x * 256 + threadIdx.x;
    if (e >= N_EDGE) return;
    int d = ei[N_EDGE + e];
    int p = atomicAdd(&woff[d], 1);
    srcS[p] = ei[e];
    dstS[p] = d;
}

// ---------------- MFMA message kernel (dst-sorted edges) ----------------
// h[e][c] = relu(A[src_e][c] - pos[dst_e]·w1p[:,c]) ; g = h @ w2 + b2  (f16 MFMA, fp32 acc)
// SELF:  src=dst=item index, plain store (segment-max init incl. self-loop)
// !SELF: atomicMax into OUT[dst]  (dsts sorted -> L2-local atomics)
// Fragment layouts (mfma_f32_16x16x32_f16): A row=lane&15, k=(lane>>4)*8+j ;
// B col=lane&15, k=(lane>>4)*8+j ; C/D col=lane&15, row=(lane>>4)*4+reg.
template<int D, bool SELF>
__global__ __launch_bounds__(256, 4)
void gemm_msg_kernel(const int* __restrict__ srcA, const int* __restrict__ dstA,
                     const f16* __restrict__ A, const float* __restrict__ pos,
                     const float* __restrict__ w1p, const f16* __restrict__ w2t,
                     const float* __restrict__ b2, float* __restrict__ OUT, int nItems)
{
    constexpr int KB = D / 32;          // K blocks (K=32 per MFMA)
    constexpr int NB = D / 16;          // N blocks
    const int tid = threadIdx.x;
    const int wave = tid >> 6;
    const int lane = tid & 63;
    const int row = lane & 15;
    const int kg = lane >> 4;
    const long wbase = ((long)blockIdx.x * 4 + wave) * 32;   // 32 edges per wave

    int s[2], d[2];
    float px[2], py[2], pz[2];
#pragma unroll
    for (int mh = 0; mh < 2; ++mh) {
        long e = wbase + mh * 16 + row;
        int ss, dd;
        if constexpr (SELF) {
            ss = dd = (e < nItems) ? (int)e : 0;
        } else {
            ss = srcA[e];
            dd = dstA[e];
        }
        s[mh] = ss; d[mh] = dd;
        px[mh] = pos[(long)dd * 3 + 0];
        py[mh] = pos[(long)dd * 3 + 1];
        pz[mh] = pos[(long)dd * 3 + 2];
    }

    // build A fragments in registers (no LDS)
    f16x8 pa[2][KB];
#pragma unroll
    for (int kb = 0; kb < KB; ++kb) {
        const int c0 = kb * 32 + kg * 8;
        f16x8 a0 = *(const f16x8*)&A[(long)s[0] * D + c0];
        f16x8 a1 = *(const f16x8*)&A[(long)s[1] * D + c0];
        f16x8 h0, h1;
#pragma unroll
        for (int j = 0; j < 8; ++j) {
            float wx = w1p[c0 + j];
            float wy = w1p[D + c0 + j];
            float wz = w1p[2 * D + c0 + j];
            h0[j] = (f16)fmaxf((float)a0[j] - (px[0] * wx + py[0] * wy + pz[0] * wz), 0.0f);
            h1[j] = (f16)fmaxf((float)a1[j] - (px[1] * wx + py[1] * wy + pz[1] * wz), 0.0f);
        }
        pa[0][kb] = h0;
        pa[1][kb] = h1;
    }

    // output rows handled by this lane: r = kg*4 + reg (C/D layout)
    int dd0[4], dd1[4];
    long e0[4], e1[4];
#pragma unroll
    for (int reg = 0; reg < 4; ++reg) {
        int r = kg * 4 + reg;
        dd0[reg] = __shfl(d[0], r);
        dd1[reg] = __shfl(d[1], r);
        e0[reg] = wbase + r;
        e1[reg] = wbase + 16 + r;
    }

#pragma unroll
    for (int nb = 0; nb < NB; ++nb) {
        f32x4 acc0 = {0.0f, 0.0f, 0.0f, 0.0f};
        f32x4 acc1 = {0.0f, 0.0f, 0.0f, 0.0f};
#pragma unroll
        for (int kb = 0; kb < KB; ++kb) {
            f16x8 pb = *(const f16x8*)&w2t[(long)(nb * 16 + row) * D + kb * 32 + kg * 8];
            acc0 = __builtin_amdgcn_mfma_f32_16x16x32_f16(pa[0][kb], pb, acc0, 0, 0, 0);
            acc1 = __builtin_amdgcn_mfma_f32_16x16x32_f16(pa[1][kb], pb, acc1, 0, 0, 0);
        }
        const int col = nb * 16 + row;
        const float bb = b2[col];
#pragma unroll
        for (int reg = 0; reg < 4; ++reg) {
            float v0 = acc0[reg] + bb;
            float v1 = acc1[reg] + bb;
            if constexpr (SELF) {
                if (e0[reg] < nItems) OUT[(long)dd0[reg] * D + col] = v0;
                if (e1[reg] < nItems) OUT[(long)dd1[reg] * D + col] = v1;
            } else {
                atomicMaxF(&OUT[(long)dd0[reg] * D + col], v0);
                atomicMaxF(&OUT[(long)dd1[reg] * D + col], v1);
            }
        }
    }
}

// ---------------- projection ----------------
__global__ void proj_kernel(const float* __restrict__ pos, const float* __restrict__ proj,
                            const int* __restrict__ img_h, const int* __restrict__ img_w,
                            int* __restrict__ pix)
{
    int n = blockIdx.x * blockDim.x + threadIdx.x;
    if (n >= N_PTS) return;
    float px = pos[n * 3 + 0], py = pos[n * 3 + 1], pz = pos[n * 3 + 2];
    float h0 = proj[0] * px + proj[1] * py + proj[2]  * pz + proj[3];
    float h1 = proj[4] * px + proj[5] * py + proj[6]  * pz + proj[7];
    float h2 = proj[8] * px + proj[9] * py + proj[10] * pz + proj[11];
    int off_u = img_w[0] - IMG_W;
    int off_v = img_h[0] - IMG_H;
    int ui = (int)(short)(h0 / h2) - off_u;   // int16 truncation semantics
    int vi = (int)(short)(h1 / h2) - off_v;
    bool valid = (ui >= 0) && (vi >= 0) && (ui < IMG_W) && (vi < IMG_H);
    pix[n] = valid ? (ui * IMG_H + vi) : -1;
}

// ---------------- scatter-add (pixel-major, CHUNK channels) ----------------
__global__ __launch_bounds__(256)
void scatter_kernel(const float* __restrict__ H, const int* __restrict__ pix,
                    float* __restrict__ img, int cbase)
{
    long g = (long)blockIdx.x * blockDim.x + threadIdx.x;
    if (g >= (long)N_PTS * CHUNK) return;
    int n = (int)(g / CHUNK);
    int c = (int)(g % CHUNK);
    int p = pix[n];
    if (p < 0) return;
    atomicAdd(&img[(long)p * CHUNK + c], H[(long)n * 256 + cbase + c]);
}

// ---------------- 4x4 max-pool ----------------
__global__ __launch_bounds__(CHUNK)
void pool_kernel(const float* __restrict__ img, float* __restrict__ out, int cbase)
{
    int cell = blockIdx.x;
    int wc = cell / OH, hc = cell % OH;
    int c = threadIdx.x;
    float mx = -INFINITY;
#pragma unroll
    for (int i = 0; i < 4; ++i)
#pragma unroll
        for (int j = 0; j < 4; ++j) {
            long p = (long)(wc * 4 + i) * IMG_H + (hc * 4 + j);
            mx = fmaxf(mx, img[p * CHUNK + c]);
        }
    out[(long)(cbase + c) * (OW * OH) + wc * OH + hc] = mx;
}

extern "C" void kernel_launch(void* const* d_in, const int* in_sizes, int n_in,
                              void* d_out, int out_size, void* d_ws, size_t ws_size,
                              hipStream_t stream)
{
    const float* x     = (const float*)d_in[0];
    const float* pos   = (const float*)d_in[1];
    const int*   ei    = (const int*)d_in[2];
    const float* proj  = (const float*)d_in[4];
    const int*   img_h = (const int*)d_in[5];
    const int*   img_w = (const int*)d_in[6];
    const float* w1_1 = (const float*)d_in[7];
    const float* b1_1 = (const float*)d_in[8];
    const float* w2_1 = (const float*)d_in[9];
    const float* b2_1 = (const float*)d_in[10];
    const float* w1_2 = (const float*)d_in[11];
    const float* b1_2 = (const float*)d_in[12];
    const float* w2_2 = (const float*)d_in[13];
    const float* b2_2 = (const float*)d_in[14];
    const float* w1_3 = (const float*)d_in[15];
    const float* b1_3 = (const float*)d_in[16];
    const float* w2_3 = (const float*)d_in[17];
    const float* b2_3 = (const float*)d_in[18];
    float* out = (float*)d_out;

    // ws layout (byte offsets), lifetime-aliased; peak = 161.5 MB:
    //   HH  @ 0           : N*256*4 = 102,400,000  [self3/edge3 out]
    //   F1  @ 0           : N*128*4 =  51,200,000  [node2..node3]
    //   F0  @ 51,200,000  : N*64*4  =  25,600,000  [node1..node2]
    //   A12 @ 76,800,000  : N*128*2 =  25,600,000  [A1 then A2]
    //   A3  @ 102,400,000 : N*256*2 =  51,200,000  [node3..edge3]
    //   img @ 102,400,000 : 1216*240*32*4 = 37,355,520  [scatter; A3 dead]
    //   pix @ 153,600,000 : N*4 = 400,000
    //   w2t3 @ 154,000,000 : 131,072 ; w2t2 @ 154,131,072 : 32,768 ; w2t1 @ 154,163,840 : 8,192
    //   srcS @ 154,200,000 : 3,200,000 ; dstS @ 157,400,000 : 3,200,000
    //   hist @ 160,600,000 : 400,000 ; woff @ 161,000,000 : 400,000 ; bsum @ 161,400,000 : 2,048
    if (ws_size < 161500000ull) return;
    char* ws = (char*)d_ws;
    float* HH   = (float*)(ws + 0);
    float* F1   = (float*)(ws + 0);
    float* F0   = (float*)(ws + 51200000);
    f16*   A12  = (f16*)(ws + 76800000);
    f16*   A3   = (f16*)(ws + 102400000);
    float* img  = (float*)(ws + 102400000);
    int*   pix  = (int*)(ws + 153600000);
    f16*   w2t3 = (f16*)(ws + 154000000);
    f16*   w2t2 = (f16*)(ws + 154131072);
    f16*   w2t1 = (f16*)(ws + 154163840);
    int*   srcS = (int*)(ws + 154200000);
    int*   dstS = (int*)(ws + 157400000);
    int*   hist = (int*)(ws + 160600000);
    int*   woff = (int*)(ws + 161000000);
    int*   bsum = (int*)(ws + 161400000);

    const int NODE_BLOCKS = N_PTS / 8;            // 12500
    const int EDGE_BLOCKS = N_EDGE / 128;         // 6250 (4 waves x 32 edges)
    const int SELF_BLOCKS = (N_PTS + 127) / 128;  // 782
    const int E256 = (N_EDGE + 255) / 256;        // 3125

    // ---- edge sort by dst (graph reused by all 3 layers) ----
    hipMemsetAsync(hist, 0, N_PTS * 4, stream);
    hist_kernel<<<E256, 256, 0, stream>>>(ei, hist);
    bsum_kernel<<<BIN_BLOCKS, 256, 0, stream>>>(hist, bsum);
    scan_bsum_kernel<<<1, 512, 0, stream>>>(bsum);
    rowptr_kernel<<<BIN_BLOCKS, 256, 0, stream>>>(hist, bsum, woff);
    scatter_edges_kernel<<<E256, 256, 0, stream>>>(ei, woff, srcS, dstS);

    // prep: transposed f16 weights + projection
    cvt_w2<<<(64 * 64 + 255) / 256, 256, 0, stream>>>(w2_1, w2t1, 64);
    cvt_w2<<<(128 * 128 + 255) / 256, 256, 0, stream>>>(w2_2, w2t2, 128);
    cvt_w2<<<(256 * 256 + 255) / 256, 256, 0, stream>>>(w2_3, w2t3, 256);
    proj_kernel<<<(N_PTS + 255) / 256, 256, 0, stream>>>(pos, proj, img_h, img_w, pix);

    // layer 1 (din 4 -> 64)
    node_kernel<4, 64><<<NODE_BLOCKS, 256, 0, stream>>>(x, pos, w1_1, b1_1, A12);
    gemm_msg_kernel<64, true><<<SELF_BLOCKS, 256, 0, stream>>>(nullptr, nullptr, A12, pos, w1_1 + 4 * 64, w2t1, b2_1, F0, N_PTS);
    gemm_msg_kernel<64, false><<<EDGE_BLOCKS, 256, 0, stream>>>(srcS, dstS, A12, pos, w1_1 + 4 * 64, w2t1, b2_1, F0, N_EDGE);

    // layer 2 (64 -> 128)
    node_kernel<64, 128><<<NODE_BLOCKS, 256, 0, stream>>>(F0, pos, w1_2, b1_2, A12);
    gemm_msg_kernel<128, true><<<SELF_BLOCKS, 256, 0, stream>>>(nullptr, nullptr, A12, pos, w1_2 + 64 * 128, w2t2, b2_2, F1, N_PTS);
    gemm_msg_kernel<128, false><<<EDGE_BLOCKS, 256, 0, stream>>>(srcS, dstS, A12, pos, w1_2 + 64 * 128, w2t2, b2_2, F1, N_EDGE);

    // layer 3 (128 -> 256)
    node_kernel<128, 256><<<NODE_BLOCKS, 256, 0, stream>>>(F1, pos, w1_3, b1_3, A3);
    gemm_msg_kernel<256, true><<<SELF_BLOCKS, 256, 0, stream>>>(nullptr, nullptr, A3, pos, w1_3 + 128 * 256, w2t3, b2_3, HH, N_PTS);
    gemm_msg_kernel<256, false><<<EDGE_BLOCKS, 256, 0, stream>>>(srcS, dstS, A3, pos, w1_3 + 128 * 256, w2t3, b2_3, HH, N_EDGE);

    // scatter + pool in 32-channel chunks
    for (int cb = 0; cb < 256; cb += CHUNK) {
        hipMemsetAsync(img, 0, (size_t)IMG_W * IMG_H * CHUNK * 4, stream);
        scatter_kernel<<<(N_PTS * CHUNK) / 256, 256, 0, stream>>>(HH, pix, img, cb);
        pool_kernel<<<OW * OH, CHUNK, 0, stream>>>(img, out, cb);
    }
}

// Round 6
// 2164.646 us; speedup vs baseline: 2.4242x; 2.4242x over previous
//
#include <hip/hip_runtime.h>
#include <cstdint>

#define N_PTS 100000
#define N_EDGE 800000
#define IMG_W 1216
#define IMG_H 240
#define OW 304
#define OH 60
#define CHUNK 32
#define BIN_BLOCKS 391   // ceil(N_PTS/256)

typedef _Float16 f16;
typedef _Float16 f16x8 __attribute__((ext_vector_type(8)));
typedef float f32x4 __attribute__((ext_vector_type(4)));

__device__ __forceinline__ void atomicMaxF(float* addr, float v) {
    // float max via int max (v>=0) / uint min (v<0); exact, order-independent
    if (v >= 0.0f) atomicMax((int*)addr, __float_as_int(v));
    else atomicMin((unsigned int*)addr, __float_as_uint(v));
}

// ---------------- per-node kernel: A[n] = X[n]@w1_x + pos[n]@w1_p + b1 (f16) ----------------
template<int DIN_X, int DOUT>
__global__ __launch_bounds__(256)
void node_kernel(const float* __restrict__ X, const float* __restrict__ pos,
                 const float* __restrict__ w1, const float* __restrict__ b1,
                 f16* __restrict__ A)
{
    constexpr int M = 8;
    constexpr int R = 256 / DOUT;
    constexpr int RR = (R < 1) ? 1 : R;
    constexpr int MN = M / RR;
    const int tid = threadIdx.x;
    const int c = tid % DOUT;
    const int r = tid / DOUT;
    const long n0 = (long)blockIdx.x * M;

    __shared__ float xs[M][DIN_X];
    __shared__ float ps[M][4];

    for (int idx = tid; idx < M * DIN_X; idx += 256) {
        int m = idx / DIN_X, k = idx % DIN_X;
        long n = n0 + m;
        xs[m][k] = (n < N_PTS) ? X[n * DIN_X + k] : 0.0f;
    }
    for (int idx = tid; idx < M * 3; idx += 256) {
        int m = idx / 3, k = idx % 3;
        long n = n0 + m;
        ps[m][k] = (n < N_PTS) ? pos[n * 3 + k] : 0.0f;
    }
    __syncthreads();

    float acc[MN];
#pragma unroll
    for (int mi = 0; mi < MN; ++mi) acc[mi] = b1[c];

    for (int k = 0; k < DIN_X; ++k) {
        float wv = w1[k * DOUT + c];
#pragma unroll
        for (int mi = 0; mi < MN; ++mi)
            acc[mi] += xs[r * MN + mi][k] * wv;
    }
#pragma unroll
    for (int k = 0; k < 3; ++k) {
        float wv = w1[(DIN_X + k) * DOUT + c];
#pragma unroll
        for (int mi = 0; mi < MN; ++mi)
            acc[mi] += ps[r * MN + mi][k] * wv;
    }
#pragma unroll
    for (int mi = 0; mi < MN; ++mi) {
        long n = n0 + r * MN + mi;
        if (n < N_PTS) A[n * DOUT + c] = (f16)acc[mi];
    }
}

// ---------------- w2 -> f16 transpose: w2t[n*D+k] = (f16)w2[k*D+n] ----------------
__global__ void cvt_w2(const float* __restrict__ w2, f16* __restrict__ w2t, int D)
{
    int i = blockIdx.x * 256 + threadIdx.x;
    if (i >= D * D) return;
    int n = i / D, k = i % D;
    w2t[i] = (f16)w2[k * D + n];
}

// ---------------- counting sort of edges by dst ----------------
__global__ void hist_kernel(const int* __restrict__ ei, int* __restrict__ hist)
{
    int e = blockIdx.x * 256 + threadIdx.x;
    if (e < N_EDGE) atomicAdd(&hist[ei[N_EDGE + e]], 1);
}

__global__ void bsum_kernel(const int* __restrict__ hist, int* __restrict__ bsum)
{
    __shared__ int s[256];
    int i = blockIdx.x * 256 + threadIdx.x;
    s[threadIdx.x] = (i < N_PTS) ? hist[i] : 0;
    __syncthreads();
    for (int off = 128; off > 0; off >>= 1) {
        if (threadIdx.x < off) s[threadIdx.x] += s[threadIdx.x + off];
        __syncthreads();
    }
    if (threadIdx.x == 0) bsum[blockIdx.x] = s[0];
}

__global__ void scan_bsum_kernel(int* __restrict__ bsum)
{
    __shared__ int s[512];
    int t = threadIdx.x;
    int v = (t < BIN_BLOCKS) ? bsum[t] : 0;
    s[t] = v;
    __syncthreads();
    for (int off = 1; off < 512; off <<= 1) {
        int u = (t >= off) ? s[t - off] : 0;
        __syncthreads();
        s[t] += u;
        __syncthreads();
    }
    if (t < BIN_BLOCKS) bsum[t] = s[t] - v;   // exclusive
}

__global__ void rowptr_kernel(const int* __restrict__ hist, const int* __restrict__ bsum,
                              int* __restrict__ woff)
{
    __shared__ int s[256];
    int i = blockIdx.x * 256 + threadIdx.x;
    int v = (i < N_PTS) ? hist[i] : 0;
    s[threadIdx.x] = v;
    __syncthreads();
    for (int off = 1; off < 256; off <<= 1) {
        int u = (threadIdx.x >= off) ? s[threadIdx.x - off] : 0;
        __syncthreads();
        s[threadIdx.x] += u;
        __syncthreads();
    }
    if (i < N_PTS) woff[i] = bsum[blockIdx.x] + s[threadIdx.x] - v;  // exclusive
}

__global__ void scatter_edges_kernel(const int* __restrict__ ei, int* __restrict__ woff,
                                     int* __restrict__ srcS, int* __restrict__ dstS)
{
    int e = blockIdx.x * 256 + threadIdx.x;
    if (e >= N_EDGE) return;
    int d = ei[N_EDGE + e];
    int p = atomicAdd(&woff[d], 1);
    srcS[p] = ei[e];
    dstS[p] = d;
}

// ---------------- MFMA message kernel (dst-sorted edges + run dedup) ----------------
// h[e][c] = relu(A[src_e][c] - pos[dst_e]·w1p[:,c]) ; g = h @ w2 + b2  (f16 MFMA, fp32 acc)
// SELF:  src=dst=item index, plain store (segment-max init incl. self-loop)
// !SELF: per-lane segmented suffix-max over its 4 contiguous output rows
//        (dsts sorted -> equal-dst rows adjacent), one atomicMax per run-head.
// Fragment layouts (mfma_f32_16x16x32_f16): A row=lane&15, k=(lane>>4)*8+j ;
// B col=lane&15, k=(lane>>4)*8+j ; C/D col=lane&15, row=(lane>>4)*4+reg.
template<int D, bool SELF>
__global__ __launch_bounds__(256)
void gemm_msg_kernel(const int* __restrict__ srcA, const int* __restrict__ dstA,
                     const f16* __restrict__ A, const float* __restrict__ pos,
                     const float* __restrict__ w1p, const f16* __restrict__ w2t,
                     const float* __restrict__ b2, float* __restrict__ OUT, int nItems)
{
    constexpr int KB = D / 32;          // K blocks (K=32 per MFMA)
    constexpr int NB = D / 16;          // N blocks
    const int tid = threadIdx.x;
    const int wave = tid >> 6;
    const int lane = tid & 63;
    const int row = lane & 15;
    const int kg = lane >> 4;
    const long wbase = ((long)blockIdx.x * 4 + wave) * 32;   // 32 edges per wave

    int s[2], d[2];
    float px[2], py[2], pz[2];
#pragma unroll
    for (int mh = 0; mh < 2; ++mh) {
        long e = wbase + mh * 16 + row;
        int ss, dd;
        if constexpr (SELF) {
            ss = dd = (e < nItems) ? (int)e : 0;
        } else {
            ss = srcA[e];
            dd = dstA[e];
        }
        s[mh] = ss; d[mh] = dd;
        px[mh] = pos[(long)dd * 3 + 0];
        py[mh] = pos[(long)dd * 3 + 1];
        pz[mh] = pos[(long)dd * 3 + 2];
    }

    // build A fragments in registers (no LDS)
    f16x8 pa[2][KB];
#pragma unroll
    for (int kb = 0; kb < KB; ++kb) {
        const int c0 = kb * 32 + kg * 8;
        f16x8 a0 = *(const f16x8*)&A[(long)s[0] * D + c0];
        f16x8 a1 = *(const f16x8*)&A[(long)s[1] * D + c0];
        f16x8 h0, h1;
#pragma unroll
        for (int j = 0; j < 8; ++j) {
            float wx = w1p[c0 + j];
            float wy = w1p[D + c0 + j];
            float wz = w1p[2 * D + c0 + j];
            h0[j] = (f16)fmaxf((float)a0[j] - (px[0] * wx + py[0] * wy + pz[0] * wz), 0.0f);
            h1[j] = (f16)fmaxf((float)a1[j] - (px[1] * wx + py[1] * wy + pz[1] * wz), 0.0f);
        }
        pa[0][kb] = h0;
        pa[1][kb] = h1;
    }

    // output rows handled by this lane: r = kg*4 + reg (C/D layout)
    int dd0[4], dd1[4];
    long e0[4], e1[4];
#pragma unroll
    for (int reg = 0; reg < 4; ++reg) {
        int r = kg * 4 + reg;
        dd0[reg] = __shfl(d[0], r);
        dd1[reg] = __shfl(d[1], r);
        e0[reg] = wbase + r;
        e1[reg] = wbase + 16 + r;
    }
    // run-head flags (sorted dsts: equal-dst rows are adjacent)
    bool hd0[4], hd1[4];
    hd0[0] = true; hd1[0] = true;
#pragma unroll
    for (int reg = 1; reg < 4; ++reg) {
        hd0[reg] = (dd0[reg] != dd0[reg - 1]);
        hd1[reg] = (dd1[reg] != dd1[reg - 1]);
    }

#pragma unroll
    for (int nb = 0; nb < NB; ++nb) {
        f32x4 acc0 = {0.0f, 0.0f, 0.0f, 0.0f};
        f32x4 acc1 = {0.0f, 0.0f, 0.0f, 0.0f};
#pragma unroll
        for (int kb = 0; kb < KB; ++kb) {
            f16x8 pb = *(const f16x8*)&w2t[(long)(nb * 16 + row) * D + kb * 32 + kg * 8];
            acc0 = __builtin_amdgcn_mfma_f32_16x16x32_f16(pa[0][kb], pb, acc0, 0, 0, 0);
            acc1 = __builtin_amdgcn_mfma_f32_16x16x32_f16(pa[1][kb], pb, acc1, 0, 0, 0);
        }
        const int col = nb * 16 + row;
        const float bb = b2[col];
        if constexpr (SELF) {
#pragma unroll
            for (int reg = 0; reg < 4; ++reg) {
                if (e0[reg] < nItems) OUT[(long)dd0[reg] * D + col] = acc0[reg] + bb;
                if (e1[reg] < nItems) OUT[(long)dd1[reg] * D + col] = acc1[reg] + bb;
            }
        } else {
            // segmented suffix-max over this lane's 4 rows, emit only at run heads
            float v0[4], v1[4];
#pragma unroll
            for (int reg = 0; reg < 4; ++reg) { v0[reg] = acc0[reg] + bb; v1[reg] = acc1[reg] + bb; }
            float s0[4], s1[4];
            s0[3] = v0[3]; s1[3] = v1[3];
#pragma unroll
            for (int reg = 2; reg >= 0; --reg) {
                s0[reg] = hd0[reg + 1] ? v0[reg] : fmaxf(v0[reg], s0[reg + 1]);
                s1[reg] = hd1[reg + 1] ? v1[reg] : fmaxf(v1[reg], s1[reg + 1]);
            }
#pragma unroll
            for (int reg = 0; reg < 4; ++reg) {
                if (hd0[reg]) atomicMaxF(&OUT[(long)dd0[reg] * D + col], s0[reg]);
                if (hd1[reg]) atomicMaxF(&OUT[(long)dd1[reg] * D + col], s1[reg]);
            }
        }
    }
}

// ---------------- projection ----------------
__global__ void proj_kernel(const float* __restrict__ pos, const float* __restrict__ proj,
                            const int* __restrict__ img_h, const int* __restrict__ img_w,
                            int* __restrict__ pix)
{
    int n = blockIdx.x * blockDim.x + threadIdx.x;
    if (n >= N_PTS) return;
    float px = pos[n * 3 + 0], py = pos[n * 3 + 1], pz = pos[n * 3 + 2];
    float h0 = proj[0] * px + proj[1] * py + proj[2]  * pz + proj[3];
    float h1 = proj[4] * px + proj[5] * py + proj[6]  * pz + proj[7];
    float h2 = proj[8] * px + proj[9] * py + proj[10] * pz + proj[11];
    int off_u = img_w[0] - IMG_W;
    int off_v = img_h[0] - IMG_H;
    int ui = (int)(short)(h0 / h2) - off_u;   // int16 truncation semantics
    int vi = (int)(short)(h1 / h2) - off_v;
    bool valid = (ui >= 0) && (vi >= 0) && (ui < IMG_W) && (vi < IMG_H);
    pix[n] = valid ? (ui * IMG_H + vi) : -1;
}

// ---------------- scatter-add (pixel-major, CHUNK channels) ----------------
__global__ __launch_bounds__(256)
void scatter_kernel(const float* __restrict__ H, const int* __restrict__ pix,
                    float* __restrict__ img, int cbase)
{
    long g = (long)blockIdx.x * blockDim.x + threadIdx.x;
    if (g >= (long)N_PTS * CHUNK) return;
    int n = (int)(g / CHUNK);
    int c = (int)(g % CHUNK);
    int p = pix[n];
    if (p < 0) return;
    atomicAdd(&img[(long)p * CHUNK + c], H[(long)n * 256 + cbase + c]);
}

// ---------------- 4x4 max-pool ----------------
__global__ __launch_bounds__(CHUNK)
void pool_kernel(const float* __restrict__ img, float* __restrict__ out, int cbase)
{
    int cell = blockIdx.x;
    int wc = cell / OH, hc = cell % OH;
    int c = threadIdx.x;
    float mx = -INFINITY;
#pragma unroll
    for (int i = 0; i < 4; ++i)
#pragma unroll
        for (int j = 0; j < 4; ++j) {
            long p = (long)(wc * 4 + i) * IMG_H + (hc * 4 + j);
            mx = fmaxf(mx, img[p * CHUNK + c]);
        }
    out[(long)(cbase + c) * (OW * OH) + wc * OH + hc] = mx;
}

extern "C" void kernel_launch(void* const* d_in, const int* in_sizes, int n_in,
                              void* d_out, int out_size, void* d_ws, size_t ws_size,
                              hipStream_t stream)
{
    const float* x     = (const float*)d_in[0];
    const float* pos   = (const float*)d_in[1];
    const int*   ei    = (const int*)d_in[2];
    const float* proj  = (const float*)d_in[4];
    const int*   img_h = (const int*)d_in[5];
    const int*   img_w = (const int*)d_in[6];
    const float* w1_1 = (const float*)d_in[7];
    const float* b1_1 = (const float*)d_in[8];
    const float* w2_1 = (const float*)d_in[9];
    const float* b2_1 = (const float*)d_in[10];
    const float* w1_2 = (const float*)d_in[11];
    const float* b1_2 = (const float*)d_in[12];
    const float* w2_2 = (const float*)d_in[13];
    const float* b2_2 = (const float*)d_in[14];
    const float* w1_3 = (const float*)d_in[15];
    const float* b1_3 = (const float*)d_in[16];
    const float* w2_3 = (const float*)d_in[17];
    const float* b2_3 = (const float*)d_in[18];
    float* out = (float*)d_out;

    // ws layout (byte offsets), lifetime-aliased; peak = 161.5 MB (see round-5 comment)
    if (ws_size < 161500000ull) return;
    char* ws = (char*)d_ws;
    float* HH   = (float*)(ws + 0);
    float* F1   = (float*)(ws + 0);
    float* F0   = (float*)(ws + 51200000);
    f16*   A12  = (f16*)(ws + 76800000);
    f16*   A3   = (f16*)(ws + 102400000);
    float* img  = (float*)(ws + 102400000);
    int*   pix  = (int*)(ws + 153600000);
    f16*   w2t3 = (f16*)(ws + 154000000);
    f16*   w2t2 = (f16*)(ws + 154131072);
    f16*   w2t1 = (f16*)(ws + 154163840);
    int*   srcS = (int*)(ws + 154200000);
    int*   dstS = (int*)(ws + 157400000);
    int*   hist = (int*)(ws + 160600000);
    int*   woff = (int*)(ws + 161000000);
    int*   bsum = (int*)(ws + 161400000);

    const int NODE_BLOCKS = N_PTS / 8;            // 12500
    const int EDGE_BLOCKS = N_EDGE / 128;         // 6250 (4 waves x 32 edges)
    const int SELF_BLOCKS = (N_PTS + 127) / 128;  // 782
    const int E256 = (N_EDGE + 255) / 256;        // 3125

    // ---- edge sort by dst (graph reused by all 3 layers) ----
    hipMemsetAsync(hist, 0, N_PTS * 4, stream);
    hist_kernel<<<E256, 256, 0, stream>>>(ei, hist);
    bsum_kernel<<<BIN_BLOCKS, 256, 0, stream>>>(hist, bsum);
    scan_bsum_kernel<<<1, 512, 0, stream>>>(bsum);
    rowptr_kernel<<<BIN_BLOCKS, 256, 0, stream>>>(hist, bsum, woff);
    scatter_edges_kernel<<<E256, 256, 0, stream>>>(ei, woff, srcS, dstS);

    // prep: transposed f16 weights + projection
    cvt_w2<<<(64 * 64 + 255) / 256, 256, 0, stream>>>(w2_1, w2t1, 64);
    cvt_w2<<<(128 * 128 + 255) / 256, 256, 0, stream>>>(w2_2, w2t2, 128);
    cvt_w2<<<(256 * 256 + 255) / 256, 256, 0, stream>>>(w2_3, w2t3, 256);
    proj_kernel<<<(N_PTS + 255) / 256, 256, 0, stream>>>(pos, proj, img_h, img_w, pix);

    // layer 1 (din 4 -> 64)
    node_kernel<4, 64><<<NODE_BLOCKS, 256, 0, stream>>>(x, pos, w1_1, b1_1, A12);
    gemm_msg_kernel<64, true><<<SELF_BLOCKS, 256, 0, stream>>>(nullptr, nullptr, A12, pos, w1_1 + 4 * 64, w2t1, b2_1, F0, N_PTS);
    gemm_msg_kernel<64, false><<<EDGE_BLOCKS, 256, 0, stream>>>(srcS, dstS, A12, pos, w1_1 + 4 * 64, w2t1, b2_1, F0, N_EDGE);

    // layer 2 (64 -> 128)
    node_kernel<64, 128><<<NODE_BLOCKS, 256, 0, stream>>>(F0, pos, w1_2, b1_2, A12);
    gemm_msg_kernel<128, true><<<SELF_BLOCKS, 256, 0, stream>>>(nullptr, nullptr, A12, pos, w1_2 + 64 * 128, w2t2, b2_2, F1, N_PTS);
    gemm_msg_kernel<128, false><<<EDGE_BLOCKS, 256, 0, stream>>>(srcS, dstS, A12, pos, w1_2 + 64 * 128, w2t2, b2_2, F1, N_EDGE);

    // layer 3 (128 -> 256)
    node_kernel<128, 256><<<NODE_BLOCKS, 256, 0, stream>>>(F1, pos, w1_3, b1_3, A3);
    gemm_msg_kernel<256, true><<<SELF_BLOCKS, 256, 0, stream>>>(nullptr, nullptr, A3, pos, w1_3 + 128 * 256, w2t3, b2_3, HH, N_PTS);
    gemm_msg_kernel<256, false><<<EDGE_BLOCKS, 256, 0, stream>>>(srcS, dstS, A3, pos, w1_3 + 128 * 256, w2t3, b2_3, HH, N_EDGE);

    // scatter + pool in 32-channel chunks
    for (int cb = 0; cb < 256; cb += CHUNK) {
        hipMemsetAsync(img, 0, (size_t)IMG_W * IMG_H * CHUNK * 4, stream);
        scatter_kernel<<<(N_PTS * CHUNK) / 256, 256, 0, stream>>>(HH, pix, img, cb);
        pool_kernel<<<OW * OH, CHUNK, 0, stream>>>(img, out, cb);
    }
}